// Round 1
// baseline (418.149 us; speedup 1.0000x reference)
//
#include <hip/hip_runtime.h>

typedef _Float16 f16;
typedef _Float16 half8 __attribute__((ext_vector_type(8)));
typedef float f32x4 __attribute__((ext_vector_type(4)));

#define MFMA16(a, b, c) __builtin_amdgcn_mfma_f32_16x16x32_f16((a), (b), (c), 0, 0, 0)

// Sizes
// B=4, CI=64, H=W=128 ; conv out 64x64 ; C=160 ; S=4097 ; SQ=4096 ; NH=4 ; HD=40
// q/k layout: [bh(16)][s(4097)][64]  (d padded to 64, pad zeroed via memset)
// vt layout:  [bh(16)][d(40)][4160]
// f layout:   [b(4)][s(4097)][160] fp16
// cat layout: [b(4)][s(4096)][160] fp32

// ---------------- K0: prep (w2 transpose, wq/wk/wv -> fp16, f pad row) ----------------
__global__ __launch_bounds__(256) void k_prep(
    const float* __restrict__ w2, const float* __restrict__ pe,
    const float* __restrict__ wq, const float* __restrict__ wk, const float* __restrict__ wv,
    float* __restrict__ w2t, f16* __restrict__ wqh, f16* __restrict__ wkh, f16* __restrict__ wvh,
    f16* __restrict__ f_h) {
  int i = blockIdx.x * 256 + threadIdx.x;
  if (i < 10240) {                       // w2t[co][c2] = w2[c2][co]
    int co = i / 160, c2 = i - co * 160;
    w2t[co * 160 + c2] = w2[c2 * 64 + co];
  } else if (i < 87040) {                // wq/wk/wv -> fp16
    int j = i - 10240;
    int kind = j / 25600, r = j - kind * 25600;
    const float* s = (kind == 0) ? wq : (kind == 1 ? wk : wv);
    f16* d = (kind == 0) ? wqh : (kind == 1 ? wkh : wvh);
    d[r] = (f16)s[r];
  } else if (i < 87680) {                // f[b][4096][c] = pe[4096]
    int j = i - 87040;
    int bb = j / 160, c = j - bb * 160;
    f_h[(bb * 4097 + 4096) * 160 + c] = (f16)pe[4096];
  }
}

// ---------------- K1: conv1(2x2 s2) + b1 + conv2(1x1) + b2 + leaky + pe -> f fp16 ----------------
__global__ __launch_bounds__(256) void k_conv(
    const float* __restrict__ x, const float* __restrict__ w1, const float* __restrict__ b1,
    const float* __restrict__ w2t, const float* __restrict__ b2, const float* __restrict__ pe,
    f16* __restrict__ f_h) {
  __shared__ float xin[32 * 4 * 64];  // [ci_local][r*2+par][xh] 32 KB
  __shared__ float c1[64 * 64];       // conv1 out [co][x] 16 KB
  int y = blockIdx.x, b = blockIdx.y;
  int t = threadIdx.x, lane = t & 63, wv = t >> 6;
  const float* xb = x + (b * 64) * 16384 + (2 * y) * 128;

  int cob = __builtin_amdgcn_readfirstlane(wv * 16);  // uniform -> s_loads for weights
  float acc[16];
#pragma unroll
  for (int j = 0; j < 16; ++j) acc[j] = b1[cob + j];

  for (int half = 0; half < 2; ++half) {
    __syncthreads();
    for (int k = 0; k < 32; ++k) {
      int i = t + (k << 8);
      int cil = i >> 8, rem = i & 255, r = rem >> 7, col = rem & 127;
      xin[(cil * 4 + r * 2 + (col & 1)) * 64 + (col >> 1)] =
          xb[(half * 32 + cil) * 16384 + r * 128 + col];
    }
    __syncthreads();
    for (int cil = 0; cil < 32; ++cil) {
      int ci = half * 32 + cil;
      float x00 = xin[(cil * 4 + 0) * 64 + lane];
      float x01 = xin[(cil * 4 + 1) * 64 + lane];
      float x10 = xin[(cil * 4 + 2) * 64 + lane];
      float x11 = xin[(cil * 4 + 3) * 64 + lane];
      const float* wr = w1 + (cob * 64 + ci) * 4;
#pragma unroll
      for (int j = 0; j < 16; ++j) {
        acc[j] += wr[j * 256 + 0] * x00 + wr[j * 256 + 1] * x01 +
                  wr[j * 256 + 2] * x10 + wr[j * 256 + 3] * x11;
      }
    }
  }
#pragma unroll
  for (int j = 0; j < 16; ++j) c1[(cob + j) * 64 + lane] = acc[j];
  __syncthreads();

  int c2b = __builtin_amdgcn_readfirstlane(wv * 40);
  float a2[40];
#pragma unroll
  for (int j = 0; j < 40; ++j) a2[j] = b2[c2b + j];
  for (int co = 0; co < 64; ++co) {
    float xv = c1[co * 64 + lane];
    const float* wr = w2t + co * 160 + c2b;  // uniform -> s_loads
#pragma unroll
    for (int j = 0; j < 40; ++j) a2[j] += xv * wr[j];
  }
  int s = y * 64 + lane;
  float pes = pe[s];
  f16* dst = f_h + (b * 4097 + s) * 160 + c2b;
#pragma unroll
  for (int j = 0; j < 40; ++j) {
    float v = a2[j];
    v = (v >= 0.f) ? v : 0.01f * v;  // leaky relu BEFORE pe add (matches ref)
    v += pes;
    dst[j] = (f16)v;
  }
}

// ---------------- K2: QKV gemms via MFMA ----------------
__global__ __launch_bounds__(256) void k_qkv(
    const f16* __restrict__ f_h,
    const f16* __restrict__ wqh, const f16* __restrict__ wkh, const f16* __restrict__ wvh,
    f16* __restrict__ q_h, f16* __restrict__ k_h, f16* __restrict__ vt_h) {
  __shared__ __attribute__((aligned(16))) f16 fT[64 * 168];  // 21.5 KB, +8 pad
  __shared__ __attribute__((aligned(16))) f16 wT[80 * 168];  // 26.9 KB, half of one weight
  int sb = blockIdx.x, b = blockIdx.y;
  int s0 = sb * 64;
  int t = threadIdx.x, lane = t & 63, wv = t >> 6, quad = lane >> 4, col = lane & 15;

  for (int c = t; c < 1280; c += 256) {  // 64 rows x 20 chunks(16B)
    int row = c / 20, seg = c - row * 20;
    int srow = s0 + row; if (srow > 4096) srow = 4096;
    *(uint4*)(fT + row * 168 + seg * 8) =
        *(const uint4*)(f_h + (b * 4097 + srow) * 160 + seg * 8);
  }
  __syncthreads();
  half8 af[5];
  int rowA = wv * 16 + col;
#pragma unroll
  for (int kk = 0; kk < 5; ++kk)
    af[kk] = *(half8*)(fT + rowA * 168 + kk * 32 + quad * 8);

  for (int kind = 0; kind < 3; ++kind) {
    const f16* wsp = (kind == 0) ? wqh : (kind == 1 ? wkh : wvh);
    for (int hf = 0; hf < 2; ++hf) {
      __syncthreads();
      for (int c = t; c < 1600; c += 256) {  // 80 rows x 20 chunks
        int row = c / 20, seg = c - row * 20;
        *(uint4*)(wT + row * 168 + seg * 8) =
            *(const uint4*)(wsp + (hf * 80 + row) * 160 + seg * 8);
      }
      __syncthreads();
#pragma unroll
      for (int n0 = 0; n0 < 5; ++n0) {
        f32x4 acc; acc[0] = 0.f; acc[1] = 0.f; acc[2] = 0.f; acc[3] = 0.f;
        int rowB = n0 * 16 + col;
#pragma unroll
        for (int kk = 0; kk < 5; ++kk) {
          half8 bf = *(half8*)(wT + rowB * 168 + kk * 32 + quad * 8);
          acc = MFMA16(af[kk], bf, acc);
        }
        int o = (hf * 5 + n0) * 16 + col;
        int hh = o / 40, d = o - hh * 40;
        int bh = b * 4 + hh;
#pragma unroll
        for (int r = 0; r < 4; ++r) {
          int s = s0 + wv * 16 + quad * 4 + r;
          if (s <= 4096) {
            f16 v = (f16)acc[r];
            if (kind == 0)      q_h[(bh * 4097 + s) * 64 + d] = v;
            else if (kind == 1) k_h[(bh * 4097 + s) * 64 + d] = v;
            else                vt_h[(bh * 40 + d) * 4160 + s] = v;
          }
        }
      }
    }
  }
}

// ---------------- K3: flash attention ----------------
__global__ __launch_bounds__(256) void k_attn(
    const f16* __restrict__ q_h, const f16* __restrict__ k_h,
    const f16* __restrict__ vt_h, float* __restrict__ cat) {
  __shared__ __attribute__((aligned(16))) f16 Qs[64 * 72];
  __shared__ __attribute__((aligned(16))) f16 Ks[64 * 72];
  __shared__ __attribute__((aligned(16))) f16 Vs[48 * 72];
  __shared__ __attribute__((aligned(16))) f16 Ps[4][16 * 72];
  int qt = blockIdx.x, bh = blockIdx.y;
  int s0 = qt * 64;
  int t = threadIdx.x, lane = t & 63, wv = t >> 6, quad = lane >> 4, col = lane & 15;

  const f16* qb = q_h + (bh * 4097 + s0) * 64;
  for (int c = t; c < 512; c += 256) {
    int row = c >> 3, seg = c & 7;
    *(uint4*)(Qs + row * 72 + seg * 8) = *(const uint4*)(qb + row * 64 + seg * 8);
  }
  for (int i = t; i < 576; i += 256) Vs[40 * 72 + i] = (f16)0.f;  // zero d=40..47 rows

  float m_[4], l_[4];
  f32x4 o_[3];
#pragma unroll
  for (int r = 0; r < 4; ++r) { m_[r] = -1e30f; l_[r] = 0.f; }
#pragma unroll
  for (int nv = 0; nv < 3; ++nv)
#pragma unroll
    for (int r = 0; r < 4; ++r) o_[nv][r] = 0.f;

  __syncthreads();
  half8 aq[2];
#pragma unroll
  for (int kk = 0; kk < 2; ++kk)
    aq[kk] = *(half8*)(Qs + (wv * 16 + col) * 72 + kk * 32 + quad * 8);

  const float scale = 0.15811388300841898f;  // 1/sqrt(40)
  for (int kt = 0; kt < 65; ++kt) {
    int k0 = kt * 64;
    __syncthreads();
    for (int c = t; c < 512; c += 256) {
      int row = c >> 3, seg = c & 7;
      int sg = k0 + row; if (sg > 4096) sg = 4096;
      *(uint4*)(Ks + row * 72 + seg * 8) =
          *(const uint4*)(k_h + (bh * 4097 + sg) * 64 + seg * 8);
    }
    for (int c = t; c < 320; c += 256) {  // 40 d-rows x 8 chunks
      int row = c >> 3, seg = c & 7;
      *(uint4*)(Vs + row * 72 + seg * 8) =
          *(const uint4*)(vt_h + (bh * 40 + row) * 4160 + k0 + seg * 8);
    }
    __syncthreads();

    f32x4 sf[4];
#pragma unroll
    for (int n0 = 0; n0 < 4; ++n0) {
      f32x4 acc; acc[0] = 0.f; acc[1] = 0.f; acc[2] = 0.f; acc[3] = 0.f;
#pragma unroll
      for (int kk = 0; kk < 2; ++kk) {
        half8 bf = *(half8*)(Ks + (n0 * 16 + col) * 72 + kk * 32 + quad * 8);
        acc = MFMA16(aq[kk], bf, acc);
      }
      sf[n0] = acc;
    }
    float mn[4];
#pragma unroll
    for (int r = 0; r < 4; ++r) mn[r] = m_[r];
#pragma unroll
    for (int n0 = 0; n0 < 4; ++n0) {
      int key = k0 + n0 * 16 + col;
      bool ok = key < 4097;
#pragma unroll
      for (int r = 0; r < 4; ++r) {
        float v = ok ? sf[n0][r] * scale : -1e30f;
        sf[n0][r] = v;
        mn[r] = fmaxf(mn[r], v);
      }
    }
#pragma unroll
    for (int r = 0; r < 4; ++r) {
      mn[r] = fmaxf(mn[r], __shfl_xor(mn[r], 1));
      mn[r] = fmaxf(mn[r], __shfl_xor(mn[r], 2));
      mn[r] = fmaxf(mn[r], __shfl_xor(mn[r], 4));
      mn[r] = fmaxf(mn[r], __shfl_xor(mn[r], 8));
    }
    float al[4], rs[4];
#pragma unroll
    for (int r = 0; r < 4; ++r) {
      al[r] = __expf(m_[r] - mn[r]); m_[r] = mn[r]; rs[r] = 0.f;
    }
#pragma unroll
    for (int n0 = 0; n0 < 4; ++n0)
#pragma unroll
      for (int r = 0; r < 4; ++r) {
        float p = __expf(sf[n0][r] - m_[r]);
        sf[n0][r] = p; rs[r] += p;
      }
#pragma unroll
    for (int r = 0; r < 4; ++r) {
      rs[r] += __shfl_xor(rs[r], 1);
      rs[r] += __shfl_xor(rs[r], 2);
      rs[r] += __shfl_xor(rs[r], 4);
      rs[r] += __shfl_xor(rs[r], 8);
      l_[r] = l_[r] * al[r] + rs[r];
    }
#pragma unroll
    for (int nv = 0; nv < 3; ++nv)
#pragma unroll
      for (int r = 0; r < 4; ++r) o_[nv][r] *= al[r];

    f16* pw = &Ps[wv][0];  // per-wave: C-layout write, A-layout read (in-order LDS)
#pragma unroll
    for (int n0 = 0; n0 < 4; ++n0)
#pragma unroll
      for (int r = 0; r < 4; ++r)
        pw[(quad * 4 + r) * 72 + n0 * 16 + col] = (f16)sf[n0][r];

#pragma unroll
    for (int kk = 0; kk < 2; ++kk) {
      half8 ap = *(half8*)(pw + col * 72 + kk * 32 + quad * 8);
#pragma unroll
      for (int nv = 0; nv < 3; ++nv) {
        half8 bv = *(half8*)(Vs + (nv * 16 + col) * 72 + kk * 32 + quad * 8);
        o_[nv] = MFMA16(ap, bv, o_[nv]);
      }
    }
  }

  int b = bh >> 2, h = bh & 3;
#pragma unroll
  for (int nv = 0; nv < 3; ++nv) {
    int d = nv * 16 + col;
    if (d < 40) {
#pragma unroll
      for (int r = 0; r < 4; ++r) {
        int s = s0 + wv * 16 + quad * 4 + r;
        cat[(b * 4096 + s) * 160 + h * 40 + d] = o_[nv][r] / l_[r];
      }
    }
  }
}

// ---------------- K4: LayerNorm + residual + 2x nearest upsample ----------------
__global__ __launch_bounds__(256) void k_ln_out(
    const float* __restrict__ cat, const float* __restrict__ lnw,
    const float* __restrict__ lnb, float* __restrict__ out) {
  __shared__ float g[64 * 161];
  int y = blockIdx.x, b = blockIdx.y, t = threadIdx.x;
  for (int i = t; i < 10240; i += 256) {
    int row = i / 160, c = i - row * 160;
    g[row * 161 + c] = cat[(b * 4096 + y * 64 + row) * 160 + c];
  }
  __syncthreads();
  int row = t >> 2, part = t & 3;
  float* gr = g + row * 161 + part * 40;
  float s1 = 0.f, s2 = 0.f;
#pragma unroll
  for (int j = 0; j < 40; ++j) { float v = gr[j]; s1 += v; s2 += v * v; }
  s1 += __shfl_xor(s1, 1); s1 += __shfl_xor(s1, 2);
  s2 += __shfl_xor(s2, 1); s2 += __shfl_xor(s2, 2);
  float mu = s1 * (1.f / 160.f);
  float var = s2 * (1.f / 160.f) - mu * mu;
  float inv = rsqrtf(var + 1e-5f);
  const float* lw = lnw + part * 40;
  const float* lb = lnb + part * 40;
#pragma unroll
  for (int j = 0; j < 40; ++j) {
    float v = gr[j];
    gr[j] = (v - mu) * inv * lw[j] + lb[j] + v;
  }
  __syncthreads();
  int Yo = t >> 7, X = t & 127, rl = X >> 1;
  float* ob = out + ((b * 160) * 128 + (2 * y + Yo)) * 128 + X;
#pragma unroll 4
  for (int c = 0; c < 160; ++c) ob[c * 16384] = g[rl * 161 + c];
}

extern "C" void kernel_launch(void* const* d_in, const int* in_sizes, int n_in,
                              void* d_out, int out_size, void* d_ws, size_t ws_size,
                              hipStream_t stream) {
  const float* x   = (const float*)d_in[0];
  const float* w1  = (const float*)d_in[1];
  const float* b1  = (const float*)d_in[2];
  const float* w2  = (const float*)d_in[3];
  const float* b2  = (const float*)d_in[4];
  const float* pe  = (const float*)d_in[5];
  const float* wq  = (const float*)d_in[6];
  const float* wk  = (const float*)d_in[7];
  const float* wvp = (const float*)d_in[8];
  const float* lnw = (const float*)d_in[9];
  const float* lnb = (const float*)d_in[10];
  float* out = (float*)d_out;

  char* p = (char*)d_ws;
  f16* f_h  = (f16*)p;  p += 4 * 4097 * 160 * 2;   // 5,244,160
  float* w2t = (float*)p; p += 64 * 160 * 4;       // 40,960
  f16* wqh  = (f16*)p;  p += 160 * 160 * 2;
  f16* wkh  = (f16*)p;  p += 160 * 160 * 2;
  f16* wvh  = (f16*)p;  p += 160 * 160 * 2;
  f16* q_h  = (f16*)p;  p += 16 * 4097 * 64 * 2;   // 8,390,656
  f16* k_h  = (f16*)p;  p += 16 * 4097 * 64 * 2;
  f16* vt_h = (f16*)p;  p += 16 * 40 * 4160 * 2;   // 5,324,800
  float* cat = (float*)p; p += 4 * 4096 * 160 * 4; // 10,485,760
  // total ~38.0 MB

  // zero q/k pads (d=40..63) so pad dims contribute exactly 0 to scores
  hipMemsetAsync(q_h, 0, (size_t)2 * 16 * 4097 * 64 * 2, stream);

  k_prep<<<343, 256, 0, stream>>>(w2, pe, wq, wk, wvp, w2t, wqh, wkh, wvh, f_h);
  k_conv<<<dim3(64, 4), 256, 0, stream>>>(x, w1, b1, w2t, b2, pe, f_h);
  k_qkv<<<dim3(65, 4), 256, 0, stream>>>(f_h, wqh, wkh, wvh, q_h, k_h, vt_h);
  k_attn<<<dim3(64, 16), 256, 0, stream>>>(q_h, k_h, vt_h, cat);
  k_ln_out<<<dim3(64, 4), 256, 0, stream>>>(cat, lnw, lnb, out);
}

// Round 5
// 282.531 us; speedup vs baseline: 1.4800x; 1.4800x over previous
//
#include <hip/hip_runtime.h>

typedef _Float16 f16;
typedef _Float16 half2v __attribute__((ext_vector_type(2)));
typedef _Float16 half4v __attribute__((ext_vector_type(4)));
typedef _Float16 half8 __attribute__((ext_vector_type(8)));
typedef float f32x4 __attribute__((ext_vector_type(4)));

#define MFMA16(a, b, c) __builtin_amdgcn_mfma_f32_16x16x32_f16((a), (b), (c), 0, 0, 0)

// Sizes
// B=4, CI=64, H=W=128 ; conv out 64x64 ; C=160 ; S=4097 ; SQ=4096 ; NH=4 ; HD=40
// q/k layout: [bh(16)][s(4097)][64]  (d padded to 64, pad zeroed via memset)
// vt layout:  [bh(16)][d(40)][4160]
// f layout:   [b(4)][s(4097)][160] fp16
// cat layout: [b(4)][s(4096)][160] fp32
// mfix layout: [bh(16)][s(4096)] fp32 = |q|*maxK*scale*log2e - 14
//   (Delta=14 boost keeps f16 P out of subnormals; P <= 2^14 < 65504 so no overflow)

// ---------------- K0: prep (w2 transpose, wq/wk/wv -> fp16, f pad row, maxk2 init) ------
__global__ __launch_bounds__(256) void k_prep(
    const float* __restrict__ w2, const float* __restrict__ pe,
    const float* __restrict__ wq, const float* __restrict__ wk, const float* __restrict__ wv,
    float* __restrict__ w2t, f16* __restrict__ wqh, f16* __restrict__ wkh, f16* __restrict__ wvh,
    f16* __restrict__ f_h, int* __restrict__ maxk2) {
  int i = blockIdx.x * 256 + threadIdx.x;
  if (i < 10240) {                       // w2t[co][c2] = w2[c2][co]
    int co = i / 160, c2 = i - co * 160;
    w2t[co * 160 + c2] = w2[c2 * 64 + co];
  } else if (i < 87040) {                // wq/wk/wv -> fp16
    int j = i - 10240;
    int kind = j / 25600, r = j - kind * 25600;
    const float* s = (kind == 0) ? wq : (kind == 1 ? wk : wv);
    f16* d = (kind == 0) ? wqh : (kind == 1 ? wkh : wvh);
    d[r] = (f16)s[r];
  } else if (i < 87680) {                // f[b][4096][c] = pe[4096]
    int j = i - 87040;
    int bb = j / 160, c = j - bb * 160;
    f_h[(bb * 4097 + 4096) * 160 + c] = (f16)pe[4096];
  } else if (i < 87696) {                // maxk2 init (0 as int == 0.0f; sums are > 0)
    maxk2[i - 87680] = 0;
  }
}

// ---------------- K1: conv1(2x2 s2) + b1 + conv2(1x1) + b2 + leaky + pe -> f fp16 -------
__global__ __launch_bounds__(256) void k_conv(
    const float* __restrict__ x, const float* __restrict__ w1, const float* __restrict__ b1,
    const float* __restrict__ w2t, const float* __restrict__ b2, const float* __restrict__ pe,
    f16* __restrict__ f_h) {
  __shared__ float xin[32 * 4 * 64];
  __shared__ float c1[64 * 64];
  int y = blockIdx.x, b = blockIdx.y;
  int t = threadIdx.x, lane = t & 63, wv = t >> 6;
  const float* xb = x + (b * 64) * 16384 + (2 * y) * 128;

  int cob = __builtin_amdgcn_readfirstlane(wv * 16);
  float acc[16];
#pragma unroll
  for (int j = 0; j < 16; ++j) acc[j] = b1[cob + j];

  for (int half = 0; half < 2; ++half) {
    __syncthreads();
    for (int k = 0; k < 32; ++k) {
      int i = t + (k << 8);
      int cil = i >> 8, rem = i & 255, r = rem >> 7, col = rem & 127;
      xin[(cil * 4 + r * 2 + (col & 1)) * 64 + (col >> 1)] =
          xb[(half * 32 + cil) * 16384 + r * 128 + col];
    }
    __syncthreads();
    for (int cil = 0; cil < 32; ++cil) {
      int ci = half * 32 + cil;
      float x00 = xin[(cil * 4 + 0) * 64 + lane];
      float x01 = xin[(cil * 4 + 1) * 64 + lane];
      float x10 = xin[(cil * 4 + 2) * 64 + lane];
      float x11 = xin[(cil * 4 + 3) * 64 + lane];
      const float* wr = w1 + (cob * 64 + ci) * 4;
#pragma unroll
      for (int j = 0; j < 16; ++j) {
        acc[j] += wr[j * 256 + 0] * x00 + wr[j * 256 + 1] * x01 +
                  wr[j * 256 + 2] * x10 + wr[j * 256 + 3] * x11;
      }
    }
  }
#pragma unroll
  for (int j = 0; j < 16; ++j) c1[(cob + j) * 64 + lane] = acc[j];
  __syncthreads();

  int c2b = __builtin_amdgcn_readfirstlane(wv * 40);
  float a2[40];
#pragma unroll
  for (int j = 0; j < 40; ++j) a2[j] = b2[c2b + j];
  for (int co = 0; co < 64; ++co) {
    float xv = c1[co * 64 + lane];
    const float* wr = w2t + co * 160 + c2b;
#pragma unroll
    for (int j = 0; j < 40; ++j) a2[j] += xv * wr[j];
  }
  int s = y * 64 + lane;
  float pes = pe[s];
  f16* dst = f_h + (b * 4097 + s) * 160 + c2b;
#pragma unroll
  for (int j = 0; j < 40; ++j) {
    float v = a2[j];
    v = (v >= 0.f) ? v : 0.01f * v;
    v += pes;
    dst[j] = (f16)v;
  }
}

// ---------------- K2: QKV gemms via MFMA ----------------
__global__ __launch_bounds__(256) void k_qkv(
    const f16* __restrict__ f_h,
    const f16* __restrict__ wqh, const f16* __restrict__ wkh, const f16* __restrict__ wvh,
    f16* __restrict__ q_h, f16* __restrict__ k_h, f16* __restrict__ vt_h) {
  __shared__ __attribute__((aligned(16))) f16 fT[64 * 168];
  __shared__ __attribute__((aligned(16))) f16 wT[80 * 168];
  int sb = blockIdx.x, b = blockIdx.y;
  int s0 = sb * 64;
  int t = threadIdx.x, lane = t & 63, wv = t >> 6, quad = lane >> 4, col = lane & 15;

  for (int c = t; c < 1280; c += 256) {
    int row = c / 20, seg = c - row * 20;
    int srow = s0 + row; if (srow > 4096) srow = 4096;
    *(uint4*)(fT + row * 168 + seg * 8) =
        *(const uint4*)(f_h + (b * 4097 + srow) * 160 + seg * 8);
  }
  __syncthreads();
  half8 af[5];
  int rowA = wv * 16 + col;
#pragma unroll
  for (int kk = 0; kk < 5; ++kk)
    af[kk] = *(half8*)(fT + rowA * 168 + kk * 32 + quad * 8);

  for (int kind = 0; kind < 3; ++kind) {
    const f16* wsp = (kind == 0) ? wqh : (kind == 1 ? wkh : wvh);
    for (int hf = 0; hf < 2; ++hf) {
      __syncthreads();
      for (int c = t; c < 1600; c += 256) {
        int row = c / 20, seg = c - row * 20;
        *(uint4*)(wT + row * 168 + seg * 8) =
            *(const uint4*)(wsp + (hf * 80 + row) * 160 + seg * 8);
      }
      __syncthreads();
#pragma unroll
      for (int n0 = 0; n0 < 5; ++n0) {
        f32x4 acc; acc[0] = 0.f; acc[1] = 0.f; acc[2] = 0.f; acc[3] = 0.f;
        int rowB = n0 * 16 + col;
#pragma unroll
        for (int kk = 0; kk < 5; ++kk) {
          half8 bf = *(half8*)(wT + rowB * 168 + kk * 32 + quad * 8);
          acc = MFMA16(af[kk], bf, acc);
        }
        int o = (hf * 5 + n0) * 16 + col;
        int hh = o / 40, d = o - hh * 40;
        int bh = b * 4 + hh;
#pragma unroll
        for (int r = 0; r < 4; ++r) {
          int s = s0 + wv * 16 + quad * 4 + r;
          if (s <= 4096) {
            f16 v = (f16)acc[r];
            if (kind == 0)      q_h[(bh * 4097 + s) * 64 + d] = v;
            else if (kind == 1) k_h[(bh * 4097 + s) * 64 + d] = v;
            else                vt_h[(bh * 40 + d) * 4160 + s] = v;
          }
        }
      }
    }
  }
}

// ---------------- K2b: per-head max ||k||^2 ----------------
__global__ __launch_bounds__(256) void k_norm1(const f16* __restrict__ k_h,
                                               int* __restrict__ maxk2) {
  int bh = blockIdx.x >> 2, chunk = blockIdx.x & 3;
  int t = threadIdx.x;
  int lo = chunk * 1025, hi = lo + 1025; if (hi > 4097) hi = 4097;
  float mx = 0.f;
  for (int i = lo + t; i < hi; i += 256) {
    const f16* kr = k_h + ((size_t)bh * 4097 + i) * 64;
    float s = 0.f;
#pragma unroll
    for (int c = 0; c < 5; ++c) {
      half8 v = *(const half8*)(kr + c * 8);
#pragma unroll
      for (int j = 0; j < 8; ++j) { float f = (float)v[j]; s += f * f; }
    }
    mx = fmaxf(mx, s);
  }
#pragma unroll
  for (int d = 1; d < 64; d <<= 1) mx = fmaxf(mx, __shfl_xor(mx, d));
  __shared__ float red[4];
  if ((t & 63) == 0) red[t >> 6] = mx;
  __syncthreads();
  if (t == 0) {
    float m = fmaxf(fmaxf(red[0], red[1]), fmaxf(red[2], red[3]));
    atomicMax(maxk2 + bh, __float_as_int(m));
  }
}

// ---------------- K2c: per-row mfix = |q|*maxK*scale*log2e - 14 ----------------
__global__ __launch_bounds__(256) void k_norm2(const f16* __restrict__ q_h,
                                               const int* __restrict__ maxk2,
                                               float* __restrict__ mfix_l) {
  int bh = blockIdx.x >> 2, chunk = blockIdx.x & 3;
  int t = threadIdx.x;
  float mk = __int_as_float(maxk2[bh]);
  const float c1l = 0.15811388300841898f * 1.4426950408889634f;
  for (int i = chunk * 1024 + t; i < chunk * 1024 + 1024; i += 256) {
    const f16* qr = q_h + ((size_t)bh * 4097 + i) * 64;
    float s = 0.f;
#pragma unroll
    for (int c = 0; c < 5; ++c) {
      half8 v = *(const half8*)(qr + c * 8);
#pragma unroll
      for (int j = 0; j < 8; ++j) { float f = (float)v[j]; s += f * f; }
    }
    // Delta=14: boost P by 2^14 (still <= 2^14 < f16 max 65504) to avoid subnormal P
    mfix_l[bh * 4096 + i] = sqrtf(s * mk) * c1l - 14.0f;
  }
}

// ---------------- K3: flash attention, S^T layout, fixed-bound softmax ----------------
// Block: 4 waves, each wave 32 q rows -> 128 q/block. grid (32, 16).
// S^T = K·Q^T via MFMA(A=K, B=Q): lane holds q=col fixed, keys=quad*4+r (+16*mt).
// P = exp2(min(s*c1l - mfix_l[q], 14)) -- no running max/sum (Cauchy-Schwarz bound).
// l accumulated by ones-row at d=40 in Vs. P roundtrips LDS b64-write/b128-read.
__global__ __launch_bounds__(256) void k_attn(
    const f16* __restrict__ q_h, const f16* __restrict__ k_h,
    const f16* __restrict__ vt_h, const float* __restrict__ mfix_l,
    float* __restrict__ cat) {
  __shared__ __attribute__((aligned(16))) f16 Ks[2][64 * 72];  // dbuf K tile
  __shared__ __attribute__((aligned(16))) f16 Vs[2][48 * 72];  // dbuf Vt tile (+ones/zero pad)
  __shared__ __attribute__((aligned(16))) f16 Ps[4 * 32 * 72]; // per-wave P; doubles as Q stage

  int qt = blockIdx.x, bh = blockIdx.y;
  int qbase = qt * 128;
  int t = threadIdx.x, lane = t & 63, wv = t >> 6, quad = lane >> 4, col = lane & 15;
  const float c1l = 0.15811388300841898f * 1.4426950408889634f;  // scale*log2e

  // ---- stage Q (128 rows x 64 f16) into Ps region; init Vs pad rows ----
  for (int c = t; c < 1024; c += 256) {
    int row = c >> 3, seg = c & 7;
    *(uint4*)(Ps + row * 72 + seg * 8) =
        *(const uint4*)(q_h + ((size_t)bh * 4097 + qbase + row) * 64 + seg * 8);
  }
  for (int i = t; i < 1152; i += 256) {  // Vs rows 40..47, both buffers
    int buf = i / 576, j = i - buf * 576;
    int row = 40 + j / 72, c = j - (j / 72) * 72;
    Vs[buf][row * 72 + c] = (row == 40 && c < 64) ? (f16)1 : (f16)0;
  }
  // ---- prefetch tile 0 into registers ----
  uint4 rk0, rk1, rv, rv2;
  {
    int row = t >> 3, seg = t & 7;
    rk0 = *(const uint4*)(k_h + ((size_t)bh * 4097 + row) * 64 + seg * 8);
    int row1 = (t + 256) >> 3;
    rk1 = *(const uint4*)(k_h + ((size_t)bh * 4097 + row1) * 64 + seg * 8);
    rv = *(const uint4*)(vt_h + ((size_t)bh * 40 + row) * 4160 + seg * 8);
    if (wv == 0)
      rv2 = *(const uint4*)(vt_h + ((size_t)bh * 40 + row1) * 4160 + seg * 8);
  }
  __syncthreads();

  // ---- Q fragments + mfix (per-lane scalars, fixed all loop) ----
  half8 bq[2][2];
#pragma unroll
  for (int nt = 0; nt < 2; ++nt)
#pragma unroll
    for (int kk = 0; kk < 2; ++kk)
      bq[nt][kk] = *(half8*)(Ps + (wv * 32 + nt * 16 + col) * 72 + kk * 32 + quad * 8);
  float mfl[2];
#pragma unroll
  for (int nt = 0; nt < 2; ++nt)
    mfl[nt] = mfix_l[bh * 4096 + qbase + wv * 32 + nt * 16 + col];

  f32x4 o_[2][3];
#pragma unroll
  for (int a = 0; a < 2; ++a)
#pragma unroll
    for (int b2 = 0; b2 < 3; ++b2)
#pragma unroll
      for (int r = 0; r < 4; ++r) o_[a][b2][r] = 0.f;

  f16* Pw = Ps + wv * (32 * 72);
  int srow = t >> 3, sseg = t & 7, srow1 = (t + 256) >> 3;

  for (int kt = 0; kt <= 64; ++kt) {
    int bsel = kt & 1;
    // write prefetched tile kt into LDS buffer bsel (regs were loaded last iter)
    *(uint4*)(&Ks[bsel][srow * 72 + sseg * 8]) = rk0;
    *(uint4*)(&Ks[bsel][(srow + 32) * 72 + sseg * 8]) = rk1;
    *(uint4*)(&Vs[bsel][srow * 72 + sseg * 8]) = rv;
    if (wv == 0) *(uint4*)(&Vs[bsel][(srow1)*72 + sseg * 8]) = rv2;
    // issue global prefetch for tile kt+1
    if (kt < 64) {
      int k0n = (kt + 1) << 6;
      int s0g = k0n + srow; if (s0g > 4096) s0g = 4096;
      // LDS row srow+32 == srow1 holds key k0n + srow1 (the -32 offset was the R3/R4 bug)
      int s1g = k0n + srow1; if (s1g > 4096) s1g = 4096;
      rk0 = *(const uint4*)(k_h + ((size_t)bh * 4097 + s0g) * 64 + sseg * 8);
      rk1 = *(const uint4*)(k_h + ((size_t)bh * 4097 + s1g) * 64 + sseg * 8);
      rv = *(const uint4*)(vt_h + ((size_t)bh * 40 + srow) * 4160 + k0n + sseg * 8);
      if (wv == 0)
        rv2 = *(const uint4*)(vt_h + ((size_t)bh * 40 + srow1) * 4160 + k0n + sseg * 8);
    }
    __syncthreads();

    const f16* K = &Ks[bsel][0];
    const f16* V = &Vs[bsel][0];
    bool last = (kt == 64);

    // ---- S^T: acc[mt][nt], m=key tile, n=q tile ----
    f32x4 acc[4][2];
#pragma unroll
    for (int mt = 0; mt < 4; ++mt) {
      half8 ak0 = *(half8*)(K + (mt * 16 + col) * 72 + quad * 8);
      half8 ak1 = *(half8*)(K + (mt * 16 + col) * 72 + 32 + quad * 8);
#pragma unroll
      for (int nt = 0; nt < 2; ++nt) {
        f32x4 a; a[0] = 0.f; a[1] = 0.f; a[2] = 0.f; a[3] = 0.f;
        a = MFMA16(ak0, bq[nt][0], a);
        a = MFMA16(ak1, bq[nt][1], a);
        acc[mt][nt] = a;
      }
    }
    // ---- P = exp2(min(s*c1l - mfix, 14)); pack 4 keys -> b64 write ----
#pragma unroll
    for (int mt = 0; mt < 4; ++mt)
#pragma unroll
      for (int nt = 0; nt < 2; ++nt) {
        float p[4];
#pragma unroll
        for (int r = 0; r < 4; ++r) {
          float a_ = fminf(fmaf(acc[mt][nt][r], c1l, -mfl[nt]), 14.0f);
          p[r] = __builtin_amdgcn_exp2f(a_);
          if (last && (mt * 16 + quad * 4 + r) != 0) p[r] = 0.f;
        }
        half2v lo = __builtin_bit_cast(half2v, __builtin_amdgcn_cvt_pkrtz(p[0], p[1]));
        half2v hi = __builtin_bit_cast(half2v, __builtin_amdgcn_cvt_pkrtz(p[2], p[3]));
        half4v pk; pk.lo = lo; pk.hi = hi;
        *(half4v*)(Pw + (nt * 16 + col) * 72 + mt * 16 + quad * 4) = pk;
      }
    // ---- o += P·V^T  (A=P m=q, B=Vt n=d); row d=40 of V is ones -> l in col 8 of nv=2
#pragma unroll
    for (int kk2 = 0; kk2 < 2; ++kk2) {
      half8 ap0 = *(half8*)(Pw + (col)*72 + kk2 * 32 + quad * 8);
      half8 ap1 = *(half8*)(Pw + (16 + col) * 72 + kk2 * 32 + quad * 8);
#pragma unroll
      for (int nv = 0; nv < 3; ++nv) {
        half8 bv = *(half8*)(V + (nv * 16 + col) * 72 + kk2 * 32 + quad * 8);
        o_[0][nv] = MFMA16(ap0, bv, o_[0][nv]);
        o_[1][nv] = MFMA16(ap1, bv, o_[1][nv]);
      }
    }
    __syncthreads();
  }

  // ---- epilogue: l broadcast (lane col==8 of nv=2 holds row sums), store ----
  int b = bh >> 2, h = bh & 3;
  int srcl = (lane & 48) + 8;
#pragma unroll
  for (int mtq = 0; mtq < 2; ++mtq) {
    float linv[4];
#pragma unroll
    for (int r = 0; r < 4; ++r) linv[r] = 1.f / __shfl(o_[mtq][2][r], srcl);
#pragma unroll
    for (int nv = 0; nv < 3; ++nv) {
      int d = nv * 16 + col;
      if (d < 40) {
#pragma unroll
        for (int r = 0; r < 4; ++r) {
          int q = qbase + wv * 32 + mtq * 16 + quad * 4 + r;
          cat[((size_t)b * 4096 + q) * 160 + h * 40 + d] = o_[mtq][nv][r] * linv[r];
        }
      }
    }
  }
}

// ---------------- K4: LayerNorm + residual + 2x nearest upsample ----------------
__global__ __launch_bounds__(256) void k_ln_out(
    const float* __restrict__ cat, const float* __restrict__ lnw,
    const float* __restrict__ lnb, float* __restrict__ out) {
  __shared__ float g[64 * 161];
  int y = blockIdx.x, b = blockIdx.y, t = threadIdx.x;
  for (int i = t; i < 10240; i += 256) {
    int row = i / 160, c = i - row * 160;
    g[row * 161 + c] = cat[(b * 4096 + y * 64 + row) * 160 + c];
  }
  __syncthreads();
  int row = t >> 2, part = t & 3;
  float* gr = g + row * 161 + part * 40;
  float s1 = 0.f, s2 = 0.f;
#pragma unroll
  for (int j = 0; j < 40; ++j) { float v = gr[j]; s1 += v; s2 += v * v; }
  s1 += __shfl_xor(s1, 1); s1 += __shfl_xor(s1, 2);
  s2 += __shfl_xor(s2, 1); s2 += __shfl_xor(s2, 2);
  float mu = s1 * (1.f / 160.f);
  float var = s2 * (1.f / 160.f) - mu * mu;
  float inv = rsqrtf(var + 1e-5f);
  const float* lw = lnw + part * 40;
  const float* lb = lnb + part * 40;
#pragma unroll
  for (int j = 0; j < 40; ++j) {
    float v = gr[j];
    gr[j] = (v - mu) * inv * lw[j] + lb[j] + v;
  }
  __syncthreads();
  int Yo = t >> 7, X = t & 127, rl = X >> 1;
  float* ob = out + ((b * 160) * 128 + (2 * y + Yo)) * 128 + X;
#pragma unroll 4
  for (int c = 0; c < 160; ++c) ob[c * 16384] = g[rl * 161 + c];
}

extern "C" void kernel_launch(void* const* d_in, const int* in_sizes, int n_in,
                              void* d_out, int out_size, void* d_ws, size_t ws_size,
                              hipStream_t stream) {
  const float* x   = (const float*)d_in[0];
  const float* w1  = (const float*)d_in[1];
  const float* b1  = (const float*)d_in[2];
  const float* w2  = (const float*)d_in[3];
  const float* b2  = (const float*)d_in[4];
  const float* pe  = (const float*)d_in[5];
  const float* wq  = (const float*)d_in[6];
  const float* wk  = (const float*)d_in[7];
  const float* wvp = (const float*)d_in[8];
  const float* lnw = (const float*)d_in[9];
  const float* lnb = (const float*)d_in[10];
  float* out = (float*)d_out;

  char* p = (char*)d_ws;
  f16* f_h  = (f16*)p;  p += 4 * 4097 * 160 * 2;
  float* w2t = (float*)p; p += 64 * 160 * 4;
  f16* wqh  = (f16*)p;  p += 160 * 160 * 2;
  f16* wkh  = (f16*)p;  p += 160 * 160 * 2;
  f16* wvh  = (f16*)p;  p += 160 * 160 * 2;
  f16* q_h  = (f16*)p;  p += 16 * 4097 * 64 * 2;
  f16* k_h  = (f16*)p;  p += 16 * 4097 * 64 * 2;
  f16* vt_h = (f16*)p;  p += 16 * 40 * 4160 * 2;
  float* cat = (float*)p; p += 4 * 4096 * 160 * 4;
  float* mfix_l = (float*)p; p += 16 * 4096 * 4;
  int* maxk2 = (int*)p; p += 16 * 4;
  // total ~38.3 MB

  (void)hipMemsetAsync(q_h, 0, (size_t)2 * 16 * 4097 * 64 * 2, stream);

  k_prep<<<343, 256, 0, stream>>>(w2, pe, wq, wk, wvp, w2t, wqh, wkh, wvh, f_h, maxk2);
  k_conv<<<dim3(64, 4), 256, 0, stream>>>(x, w1, b1, w2t, b2, pe, f_h);
  k_qkv<<<dim3(65, 4), 256, 0, stream>>>(f_h, wqh, wkh, wvh, q_h, k_h, vt_h);
  k_norm1<<<64, 256, 0, stream>>>(k_h, maxk2);
  k_norm2<<<64, 256, 0, stream>>>(q_h, maxk2, mfix_l);
  k_attn<<<dim3(32, 16), 256, 0, stream>>>(q_h, k_h, vt_h, mfix_l, cat);
  k_ln_out<<<dim3(64, 4), 256, 0, stream>>>(cat, lnw, lnb, out);
}